// Round 9
// baseline (611.534 us; speedup 1.0000x reference)
//
#include <hip/hip_runtime.h>
#include <math.h>

#define BATCH 64
#define WW 320
#define HWTOT 76800
#define HW4 19200
#define NJTRB 512       // jtr blocks, 8 per batch
#define JSL4 2400       // float4s per jtr block (contiguous)
#define NCONV1 1280
#define KS 64
#define NSLICE 300
// DIAGNOSTIC internal repetition counts (attribution v2 — remove next round)
#define REP2 16
#define REP3 32
#define REP4 32

// ================= K1: jtr partials (blocks<NJTRB) + fused pool+conv1 =================
__global__ __launch_bounds__(256) void k_front(
    const float* __restrict__ Jt, const float* __restrict__ wgt,
    const float* __restrict__ Rin, const float* __restrict__ c1w,
    const float* __restrict__ c1b, float* __restrict__ part,
    float* __restrict__ h1) {
  __shared__ float smem[34 * 37 + 96];
  int tid = threadIdx.x;
  if (blockIdx.x < NJTRB) {
    int b = blockIdx.x >> 3, s = blockIdx.x & 7;
    const float4* w4 = (const float4*)(wgt + (size_t)b * HWTOT);
    const float4* r4 = (const float4*)(Rin + (size_t)b * HWTOT);
    const float4* j4 = (const float4*)(Jt + (size_t)b * 6 * HWTOT);
    int base = s * JSL4;
    float acc[6] = {0.f, 0.f, 0.f, 0.f, 0.f, 0.f};
#pragma unroll 3
    for (int k = 0; k < 9; ++k) {
      int t = base + k * 256 + tid;
      float4 wv = w4[t], rv = r4[t];
      float4 p;
      p.x = wv.x * rv.x; p.y = wv.y * rv.y; p.z = wv.z * rv.z; p.w = wv.w * rv.w;
#pragma unroll
      for (int i = 0; i < 6; ++i) {
        float4 jv = j4[i * HW4 + t];
        acc[i] += jv.x * p.x + jv.y * p.y + jv.z * p.z + jv.w * p.w;
      }
    }
    if (tid < 96) {  // 2400 = 9*256 + 96
      int t = base + 2304 + tid;
      float4 wv = w4[t], rv = r4[t];
      float4 p;
      p.x = wv.x * rv.x; p.y = wv.y * rv.y; p.z = wv.z * rv.z; p.w = wv.w * rv.w;
#pragma unroll
      for (int i = 0; i < 6; ++i) {
        float4 jv = j4[i * HW4 + t];
        acc[i] += jv.x * p.x + jv.y * p.y + jv.z * p.z + jv.w * p.w;
      }
    }
#pragma unroll
    for (int i = 0; i < 6; ++i) {
      float v = acc[i];
      for (int off = 32; off; off >>= 1) v += __shfl_down(v, off, 64);
      acc[i] = v;
    }
    float* sred = smem;
    int lane = tid & 63, wid = tid >> 6;
    if (lane == 0) {
#pragma unroll
      for (int i = 0; i < 6; ++i) sred[wid * 6 + i] = acc[i];
    }
    __syncthreads();
    if (tid < 6) {
      part[blockIdx.x * 6 + tid] =
          sred[0 + tid] + sred[6 + tid] + sred[12 + tid] + sred[18 + tid];
    }
    return;
  }
  // ---- fused maxpool2(R) + conv1 + relu + maxpool2 -> h1 NHWC [B,60,80,8] ----
  int cb = blockIdx.x - NJTRB;
  int b = cb / 20, rem = cb % 20;
  int by = rem / 5, bx = rem % 5;
  float (*sA)[37] = (float(*)[37])smem;
  float* sW = smem + 34 * 37;
  float* sB = sW + 72;
  if (tid < 72) sW[tid] = c1w[(tid & 7) * 9 + (tid >> 3)];
  if (tid < 8) sB[tid] = c1b[tid];
  int iy0 = 32 * by - 1;
  const float* src = Rin + (size_t)b * HWTOT;
  for (int idx = tid; idx < 34 * 18; idx += 256) {
    int pr = idx / 18, c4 = idx % 18;
    int py = iy0 + pr;
    int gx = 64 * bx - 4 + 4 * c4;
    float cell0 = 0.f, cell1 = 0.f;
    if (py >= 0 && py < 120 && gx >= 0 && gx < 320) {
      const float4* row0 = (const float4*)(src + (size_t)(2 * py) * WW + gx);
      const float4* row1 = (const float4*)(src + (size_t)(2 * py + 1) * WW + gx);
      float4 v0 = row0[0], v1 = row1[0];
      cell0 = fmaxf(fmaxf(v0.x, v0.y), fmaxf(v1.x, v1.y));
      cell1 = fmaxf(fmaxf(v0.z, v0.w), fmaxf(v1.z, v1.w));
    }
    sA[pr][2 * c4] = cell0;
    sA[pr][2 * c4 + 1] = cell1;
  }
  __syncthreads();
  int ly = tid / 16, lx = tid % 16;
  int y = 16 * by + ly, x = 16 * bx + lx;
  float win[16];
#pragma unroll
  for (int r = 0; r < 4; ++r)
#pragma unroll
    for (int c = 0; c < 4; ++c) win[r * 4 + c] = sA[2 * ly + r][2 * lx + c + 1];
  float acc[8][4];
#pragma unroll
  for (int oc = 0; oc < 8; ++oc)
#pragma unroll
    for (int p = 0; p < 4; ++p) acc[oc][p] = 0.f;
#pragma unroll
  for (int tap = 0; tap < 9; ++tap) {
    int ky = tap / 3, kx = tap % 3;
#pragma unroll
    for (int oc = 0; oc < 8; ++oc) {
      float wv = sW[tap * 8 + oc];
#pragma unroll
      for (int py = 0; py < 2; ++py)
#pragma unroll
        for (int px = 0; px < 2; ++px)
          acc[oc][py * 2 + px] += wv * win[(py + ky) * 4 + (px + kx)];
    }
  }
  if (y < 60) {
    float v[8];
#pragma unroll
    for (int oc = 0; oc < 8; ++oc)
      v[oc] = fmaxf(fmaxf(fmaxf(acc[oc][0], acc[oc][1]), fmaxf(acc[oc][2], acc[oc][3])) + sB[oc], 0.f);
    float4* dst = (float4*)(h1 + (((size_t)b * 60 + y) * 80 + x) * 8);
    dst[0] = make_float4(v[0], v[1], v[2], v[3]);
    dst[1] = make_float4(v[4], v[5], v[6], v[7]);
  }
}

// ================= K2: conv2 (R8 body; DIAGNOSTIC rep loop REP2x) =================
__global__ __launch_bounds__(256) void k_conv2(
    const float* __restrict__ h1, const float* __restrict__ c2w,
    const float* __restrict__ c2b, float* __restrict__ h2) {
  __shared__ float sA[8][34][38];
  int b = blockIdx.z >> 1, ocg = blockIdx.z & 1;
  int ty0 = blockIdx.y * 16, tx0 = blockIdx.x * 16;
  int tid = threadIdx.x;
  int iy0 = ty0 * 2 - 1, ix0 = tx0 * 2 - 1;
  const float* src = h1 + (size_t)b * 60 * 80 * 8;
  int ly = tid / 16, lx = tid % 16;
  const float* wbase = c2w + ocg * 8 * 72;
#pragma unroll 1
  for (int rep = 0; rep < REP2; ++rep) {
    __syncthreads();  // protect sA across reps
    for (int idx = tid; idx < 34 * 34; idx += 256) {
      int r = idx / 34, c = idx % 34;
      int gy = iy0 + r, gx = ix0 + c;
      float4 v0 = make_float4(0.f, 0.f, 0.f, 0.f), v1 = v0;
      if (gy >= 0 && gy < 60 && gx >= 0 && gx < 80) {
        const float4* p = (const float4*)(src + ((size_t)gy * 80 + gx) * 8);
        v0 = p[0]; v1 = p[1];
      }
      sA[0][r][c] = v0.x; sA[1][r][c] = v0.y; sA[2][r][c] = v0.z; sA[3][r][c] = v0.w;
      sA[4][r][c] = v1.x; sA[5][r][c] = v1.y; sA[6][r][c] = v1.z; sA[7][r][c] = v1.w;
    }
    __syncthreads();
    float acc[8][4];
#pragma unroll
    for (int o = 0; o < 8; ++o)
#pragma unroll
      for (int p = 0; p < 4; ++p) acc[o][p] = 0.f;
#pragma unroll
    for (int ic = 0; ic < 8; ++ic) {
      float win[16];
#pragma unroll
      for (int r = 0; r < 4; ++r)
#pragma unroll
        for (int c = 0; c < 4; ++c) win[r * 4 + c] = sA[ic][2 * ly + r][2 * lx + c];
#pragma unroll
      for (int tap = 0; tap < 9; ++tap) {
        int ky = tap / 3, kx = tap % 3;
#pragma unroll
        for (int o = 0; o < 8; ++o) {
          float wv = wbase[o * 72 + ic * 9 + tap];
#pragma unroll
          for (int py = 0; py < 2; ++py)
#pragma unroll
            for (int px = 0; px < 2; ++px)
              acc[o][py * 2 + px] += wv * win[(py + ky) * 4 + (px + kx)];
        }
      }
    }
    int y = ty0 + ly, x = tx0 + lx;
    if (y < 30 && x < 40) {
#pragma unroll
      for (int o = 0; o < 8; ++o) {
        int oc = ocg * 8 + o;
        float m = fmaxf(fmaxf(acc[o][0], acc[o][1]), fmaxf(acc[o][2], acc[o][3])) + c2b[oc];
        h2[(((size_t)b * 16 + oc) * 30 + y) * 40 + x] = fmaxf(m, 0.f);
      }
    }
  }
}

// ================= K3: fc1 partial GEMM (R8 body; DIAGNOSTIC rep loop REP3x) =================
__global__ __launch_bounds__(256) void k_fc1_part(
    const float* __restrict__ h2, const float* __restrict__ f1w,
    float* __restrict__ fcpart) {
  __shared__ __align__(16) float sH[KS * 68];
  __shared__ __align__(16) float sWt[KS * 68];
  int sl = blockIdx.x, k0 = sl * KS;
  int tid = threadIdx.x;
  int bq = tid & 15, jq = tid >> 4;
  int b0 = bq * 4, j0 = jq * 4;
#pragma unroll 1
  for (int rep = 0; rep < REP3; ++rep) {
    __syncthreads();  // protect LDS across reps
    for (int idx = tid; idx < 64 * KS; idx += 256) {
      int b = idx >> 6, kk = idx & 63;
      sH[kk * 68 + b] = h2[(size_t)b * 19200 + k0 + kk];
      sWt[kk * 68 + b] = f1w[(size_t)b * 19200 + k0 + kk];
    }
    __syncthreads();
    float acc[4][4];
#pragma unroll
    for (int i = 0; i < 4; ++i)
#pragma unroll
      for (int j = 0; j < 4; ++j) acc[i][j] = 0.f;
    for (int kk = 0; kk < KS; ++kk) {
      float4 hv = *(const float4*)&sH[kk * 68 + b0];
      float4 wv = *(const float4*)&sWt[kk * 68 + j0];
      float hb[4] = {hv.x, hv.y, hv.z, hv.w};
      float wb[4] = {wv.x, wv.y, wv.z, wv.w};
#pragma unroll
      for (int i = 0; i < 4; ++i)
#pragma unroll
        for (int j = 0; j < 4; ++j) acc[i][j] += hb[i] * wb[j];
    }
#pragma unroll
    for (int i = 0; i < 4; ++i)
#pragma unroll
      for (int j = 0; j < 4; ++j)
        fcpart[(size_t)(b0 + i) * 19200 + sl * 64 + (j0 + j)] = acc[i][j];
  }
}

// ================= K4: final (R8 body; DIAGNOSTIC rep loop REP4x) =================
__global__ __launch_bounds__(256) void k_final(
    const float* __restrict__ fcpart, const float* __restrict__ f1b,
    const float* __restrict__ f2w, const float* __restrict__ f2b,
    const float* __restrict__ consts, const float* __restrict__ part,
    const float* __restrict__ JtJ, const float* __restrict__ poseR,
    const float* __restrict__ poseT, float* __restrict__ out) {
  __shared__ __align__(16) float sred[16 * 64];
  __shared__ float fc1v[64];
  __shared__ float sf2w[384];
  __shared__ float sf2b[8];
  __shared__ float sconst[36];
  __shared__ float lg[6];
  __shared__ float lamv[6];
  __shared__ float jtrv[6];
  int b = blockIdx.x, tid = threadIdx.x;
  for (int i = tid; i < 384; i += 256) sf2w[i] = f2w[i];
  if (tid < 6) sf2b[tid] = f2b[tid];
  if (tid < 36) sconst[tid] = consts[tid];
#pragma unroll 1
  for (int rep = 0; rep < REP4; ++rep) {
    __syncthreads();  // protect smem across reps (covers const stage on rep 0)
    {
      const float4* fp4 = (const float4*)(fcpart + (size_t)b * 19200);
      int sg = tid >> 4, j4 = tid & 15;
      float4 a = make_float4(0.f, 0.f, 0.f, 0.f);
      for (int s = sg; s < NSLICE; s += 16) {
        float4 v = fp4[s * 16 + j4];
        a.x += v.x; a.y += v.y; a.z += v.z; a.w += v.w;
      }
      ((float4*)sred)[sg * 16 + j4] = a;
    }
    if (tid >= 64 && tid < 70) {
      int i = tid - 64;
      float v = 0.f;
      for (int s = 0; s < 8; ++s) v += part[(b * 8 + s) * 6 + i];
      jtrv[i] = v;
    }
    __syncthreads();
    if (tid < 64) {
      float v = 0.f;
#pragma unroll
      for (int sg = 0; sg < 16; ++sg) v += sred[sg * 64 + tid];
      fc1v[tid] = fmaxf(v + f1b[tid], 0.f);
    }
    __syncthreads();
    if (tid < 6) {
      float v = sf2b[tid];
#pragma unroll
      for (int k = 0; k < 64; ++k) v += fc1v[k] * sf2w[tid * 64 + k];
      lg[tid] = v;
    }
    __syncthreads();
    if (tid < 6) {
      float m = lg[0];
#pragma unroll
      for (int i = 1; i < 6; ++i) m = fmaxf(m, lg[i]);
      float e[6], ssum = 0.f;
#pragma unroll
      for (int i = 0; i < 6; ++i) { e[i] = expf(lg[i] - m); ssum += e[i]; }
      float inv = 1.f / ssum;
      float wc = 0.f;
#pragma unroll
      for (int i = 0; i < 6; ++i) wc += (e[i] * inv) * sconst[i * 6 + tid];
      float sg = 1.f / (1.f + expf(-wc));
      lamv[tid] = expf((-6.f + sg) * 2.302585092994046f);
    }
    __syncthreads();
    if (tid == 0) {
      float Hm[6][6];
      const float* srcH = JtJ + b * 36;
      float tr = 0.f;
#pragma unroll
      for (int i = 0; i < 6; ++i) {
#pragma unroll
        for (int jj = 0; jj < 6; ++jj) Hm[i][jj] = srcH[i * 6 + jj];
        tr += srcH[i * 6 + i];
      }
      float rhs[6];
#pragma unroll
      for (int i = 0; i < 6; ++i) {
        rhs[i] = jtrv[i];
        Hm[i][i] += lamv[i] + 1e-6f * tr + 1e-6f;
      }
      float L[6][6];
#pragma unroll
      for (int i = 0; i < 6; ++i) {
#pragma unroll
        for (int jj = 0; jj < 6; ++jj) {
          if (jj > i) continue;
          float s = Hm[i][jj];
#pragma unroll
          for (int k = 0; k < 6; ++k)
            if (k < jj) s -= L[i][k] * L[jj][k];
          if (i == jj) L[i][jj] = sqrtf(fmaxf(s, 1e-30f));
          else L[i][jj] = s / L[jj][jj];
        }
      }
      float yv[6];
#pragma unroll
      for (int i = 0; i < 6; ++i) {
        float s = rhs[i];
#pragma unroll
        for (int k = 0; k < 6; ++k)
          if (k < i) s -= L[i][k] * yv[k];
        yv[i] = s / L[i][i];
      }
      float xi[6];
#pragma unroll
      for (int ii = 5; ii >= 0; --ii) {
        float s = yv[ii];
#pragma unroll
        for (int k = 0; k < 6; ++k)
          if (k > ii) s -= L[k][ii] * xi[k];
        xi[ii] = s / L[ii][ii];
      }
      float wx = -xi[0], wy = -xi[1], wz = -xi[2];
      float th = fmaxf(sqrtf(wx * wx + wy * wy + wz * wz), 1e-12f);
      float ux = wx / th, uy = wy / th, uz = wz / th;
      float s = sinf(th), c1 = 1.f - cosf(th);
      float Rd[3][3];
      Rd[0][0] = 1.f + c1 * (ux * ux - 1.f);
      Rd[0][1] = -s * uz + c1 * (ux * uy);
      Rd[0][2] = s * uy + c1 * (ux * uz);
      Rd[1][0] = s * uz + c1 * (uy * ux);
      Rd[1][1] = 1.f + c1 * (uy * uy - 1.f);
      Rd[1][2] = -s * ux + c1 * (uy * uz);
      Rd[2][0] = -s * uy + c1 * (uz * ux);
      Rd[2][1] = s * ux + c1 * (uz * uy);
      Rd[2][2] = 1.f + c1 * (uz * uz - 1.f);
      float dt[3];
#pragma unroll
      for (int r = 0; r < 3; ++r)
        dt[r] = -(Rd[r][0] * xi[3] + Rd[r][1] * xi[4] + Rd[r][2] * xi[5]);
      const float* pR = poseR + b * 9;
      const float* pt = poseT + b * 3;
#pragma unroll
      for (int r = 0; r < 3; ++r) {
#pragma unroll
        for (int cc = 0; cc < 3; ++cc) {
          out[b * 12 + r * 4 + cc] =
              pR[r * 3 + 0] * Rd[0][cc] + pR[r * 3 + 1] * Rd[1][cc] + pR[r * 3 + 2] * Rd[2][cc];
        }
        out[b * 12 + r * 4 + 3] =
            pR[r * 3 + 0] * dt[0] + pR[r * 3 + 1] * dt[1] + pR[r * 3 + 2] * dt[2] + pt[r];
      }
    }
  }
}

extern "C" void kernel_launch(void* const* d_in, const int* in_sizes, int n_in,
                              void* d_out, int out_size, void* d_ws, size_t ws_size,
                              hipStream_t stream) {
  const float* JtJ = (const float*)d_in[0];
  const float* Jt = (const float*)d_in[1];
  const float* wts = (const float*)d_in[2];
  const float* Rin = (const float*)d_in[3];
  const float* poseR = (const float*)d_in[4];
  const float* poseT = (const float*)d_in[5];
  const float* consts = (const float*)d_in[11];
  const float* c1w = (const float*)d_in[12];
  const float* c1b = (const float*)d_in[13];
  const float* c2w = (const float*)d_in[14];
  const float* c2b = (const float*)d_in[15];
  const float* f1w = (const float*)d_in[16];
  const float* f1b = (const float*)d_in[17];
  const float* f2w = (const float*)d_in[18];
  const float* f2b = (const float*)d_in[19];
  float* ws = (float*)d_ws;
  float* part = ws;                 // 3072
  float* h1 = part + 3072;          // 2,457,600 (NHWC)
  float* h2 = h1 + 2457600;         // 1,228,800 (NCHW)
  float* fcpart = h2 + 1228800;     // 64*300*64 = 1,228,800 ([b][sl][64])
  float* out = (float*)d_out;

  k_front<<<dim3(NJTRB + NCONV1), dim3(256), 0, stream>>>(Jt, wts, Rin, c1w, c1b, part, h1);
  k_conv2<<<dim3(3, 2, BATCH * 2), dim3(256), 0, stream>>>(h1, c2w, c2b, h2);
  k_fc1_part<<<dim3(NSLICE), dim3(256), 0, stream>>>(h2, f1w, fcpart);
  k_final<<<dim3(64), dim3(256), 0, stream>>>(fcpart, f1b, f2w, f2b, consts, part,
                                              JtJ, poseR, poseT, out);
}

// Round 10
// 67.466 us; speedup vs baseline: 9.0644x; 9.0644x over previous
//
#include <hip/hip_runtime.h>
#include <math.h>

#define BATCH 64
#define WW 320
#define HWTOT 76800
#define HW4 19200
#define NJTRB 512       // jtr blocks, 8 per batch
#define JSL4 2400       // float4s per jtr block (contiguous)
#define NCONV1 1280
#define KS 64
#define NSLICE 300

typedef _Float16 half2_t __attribute__((ext_vector_type(2)));
union U32H2 { unsigned int u; half2_t h; };
__device__ __forceinline__ unsigned int pack_h2(float a, float b) {
  U32H2 x; x.h = half2_t{(_Float16)a, (_Float16)b}; return x.u;
}
__device__ __forceinline__ half2_t u_as_h2(unsigned int u) { U32H2 x; x.u = u; return x.h; }

#if defined(__has_builtin)
#if __has_builtin(__builtin_amdgcn_fdot2)
#define HAVE_FDOT2 1
#endif
#endif

__device__ __forceinline__ float dot2acc(unsigned int a, unsigned int b, float c) {
#ifdef HAVE_FDOT2
  return __builtin_amdgcn_fdot2(u_as_h2(a), u_as_h2(b), c, false);
#else
  half2_t ah = u_as_h2(a), bh = u_as_h2(b);
  return c + (float)ah.x * (float)bh.x + (float)ah.y * (float)bh.y;
#endif
}

// ================= K1: jtr partials + fused pool+conv1 (h1 -> packed f16 NHWC) ========
__global__ __launch_bounds__(256) void k_front(
    const float* __restrict__ Jt, const float* __restrict__ wgt,
    const float* __restrict__ Rin, const float* __restrict__ c1w,
    const float* __restrict__ c1b, const float* __restrict__ c2w,
    float* __restrict__ part, unsigned int* __restrict__ h1u,
    unsigned int* __restrict__ wpk) {
  __shared__ float smem[34 * 37 + 96];
  int tid = threadIdx.x;
  if (blockIdx.x < NJTRB) {
    int b = blockIdx.x >> 3, s = blockIdx.x & 7;
    const float4* w4 = (const float4*)(wgt + (size_t)b * HWTOT);
    const float4* r4 = (const float4*)(Rin + (size_t)b * HWTOT);
    const float4* j4 = (const float4*)(Jt + (size_t)b * 6 * HWTOT);
    int base = s * JSL4;
    float acc[6] = {0.f, 0.f, 0.f, 0.f, 0.f, 0.f};
#pragma unroll 3
    for (int k = 0; k < 9; ++k) {
      int t = base + k * 256 + tid;
      float4 wv = w4[t], rv = r4[t];
      float4 p;
      p.x = wv.x * rv.x; p.y = wv.y * rv.y; p.z = wv.z * rv.z; p.w = wv.w * rv.w;
#pragma unroll
      for (int i = 0; i < 6; ++i) {
        float4 jv = j4[i * HW4 + t];
        acc[i] += jv.x * p.x + jv.y * p.y + jv.z * p.z + jv.w * p.w;
      }
    }
    if (tid < 96) {
      int t = base + 2304 + tid;
      float4 wv = w4[t], rv = r4[t];
      float4 p;
      p.x = wv.x * rv.x; p.y = wv.y * rv.y; p.z = wv.z * rv.z; p.w = wv.w * rv.w;
#pragma unroll
      for (int i = 0; i < 6; ++i) {
        float4 jv = j4[i * HW4 + t];
        acc[i] += jv.x * p.x + jv.y * p.y + jv.z * p.z + jv.w * p.w;
      }
    }
#pragma unroll
    for (int i = 0; i < 6; ++i) {
      float v = acc[i];
      for (int off = 32; off; off >>= 1) v += __shfl_down(v, off, 64);
      acc[i] = v;
    }
    float* sred = smem;
    int lane = tid & 63, wid = tid >> 6;
    if (lane == 0) {
#pragma unroll
      for (int i = 0; i < 6; ++i) sred[wid * 6 + i] = acc[i];
    }
    __syncthreads();
    if (tid < 6) {
      part[blockIdx.x * 6 + tid] =
          sred[0 + tid] + sred[6 + tid] + sred[12 + tid] + sred[18 + tid];
    }
    return;
  }
  // ---- fused maxpool2(R) + conv1 + relu + maxpool2 -> h1 packed f16 NHWC ----
  int cb = blockIdx.x - NJTRB;
  int b = cb / 20, rem = cb % 20;
  int by = rem / 5, bx = rem % 5;
  // conv2 weight repack on block cb==0: wpk[icp][tap][16oc] = half2(w[2icp], w[2icp+1])
  if (cb == 0) {
    for (int i = tid; i < 576; i += 256) {
      int icp = i / 144, tap = (i % 144) / 16, oc = i % 16;
      float lo = c2w[oc * 72 + (2 * icp) * 9 + tap];
      float hi = c2w[oc * 72 + (2 * icp + 1) * 9 + tap];
      wpk[i] = pack_h2(lo, hi);
    }
  }
  float (*sA)[37] = (float(*)[37])smem;
  float* sW = smem + 34 * 37;
  float* sB = sW + 72;
  if (tid < 72) sW[tid] = c1w[(tid & 7) * 9 + (tid >> 3)];
  if (tid < 8) sB[tid] = c1b[tid];
  int iy0 = 32 * by - 1;
  const float* src = Rin + (size_t)b * HWTOT;
  for (int idx = tid; idx < 34 * 18; idx += 256) {
    int pr = idx / 18, c4 = idx % 18;
    int py = iy0 + pr;
    int gx = 64 * bx - 4 + 4 * c4;
    float cell0 = 0.f, cell1 = 0.f;
    if (py >= 0 && py < 120 && gx >= 0 && gx < 320) {
      const float4* row0 = (const float4*)(src + (size_t)(2 * py) * WW + gx);
      const float4* row1 = (const float4*)(src + (size_t)(2 * py + 1) * WW + gx);
      float4 v0 = row0[0], v1 = row1[0];
      cell0 = fmaxf(fmaxf(v0.x, v0.y), fmaxf(v1.x, v1.y));
      cell1 = fmaxf(fmaxf(v0.z, v0.w), fmaxf(v1.z, v1.w));
    }
    sA[pr][2 * c4] = cell0;
    sA[pr][2 * c4 + 1] = cell1;
  }
  __syncthreads();
  int ly = tid / 16, lx = tid % 16;
  int y = 16 * by + ly, x = 16 * bx + lx;
  float win[16];
#pragma unroll
  for (int r = 0; r < 4; ++r)
#pragma unroll
    for (int c = 0; c < 4; ++c) win[r * 4 + c] = sA[2 * ly + r][2 * lx + c + 1];
  float acc[8][4];
#pragma unroll
  for (int oc = 0; oc < 8; ++oc)
#pragma unroll
    for (int p = 0; p < 4; ++p) acc[oc][p] = 0.f;
#pragma unroll
  for (int tap = 0; tap < 9; ++tap) {
    int ky = tap / 3, kx = tap % 3;
#pragma unroll
    for (int oc = 0; oc < 8; ++oc) {
      float wv = sW[tap * 8 + oc];
#pragma unroll
      for (int py = 0; py < 2; ++py)
#pragma unroll
        for (int px = 0; px < 2; ++px)
          acc[oc][py * 2 + px] += wv * win[(py + ky) * 4 + (px + kx)];
    }
  }
  if (y < 60) {
    float v[8];
#pragma unroll
    for (int oc = 0; oc < 8; ++oc)
      v[oc] = fmaxf(fmaxf(fmaxf(acc[oc][0], acc[oc][1]), fmaxf(acc[oc][2], acc[oc][3])) + sB[oc], 0.f);
    uint4 st;
    st.x = pack_h2(v[0], v[1]);
    st.y = pack_h2(v[2], v[3]);
    st.z = pack_h2(v[4], v[5]);
    st.w = pack_h2(v[6], v[7]);
    *(uint4*)(h1u + (((size_t)b * 60 + y) * 80 + x) * 4) = st;
  }
}

// ================= K2: conv2 f16 packed dot -> h2 fp32 NCHW [B,16,30,40] ==============
// grid (3,2,B*2), z = b*2 + ocg. h1u = packed f16 NHWC (4 uints/cell).
__global__ __launch_bounds__(256) void k_conv2(
    const unsigned int* __restrict__ h1u, const unsigned int* __restrict__ wpk,
    const float* __restrict__ c2b, float* __restrict__ h2) {
  __shared__ unsigned int sA[4][34][38];   // ic-pair planes
  __shared__ __align__(16) unsigned int sW[288];  // [icp][tap][8oc of group]
  int b = blockIdx.z >> 1, ocg = blockIdx.z & 1;
  int ty0 = blockIdx.y * 16, tx0 = blockIdx.x * 16;
  int tid = threadIdx.x;
  for (int i = tid; i < 288; i += 256) {
    int icp = i / 72, tap = (i % 72) / 8, o = i % 8;
    sW[i] = wpk[icp * 144 + tap * 16 + ocg * 8 + o];
  }
  int iy0 = ty0 * 2 - 1, ix0 = tx0 * 2 - 1;
  const unsigned int* src = h1u + (size_t)b * 60 * 80 * 4;
  for (int idx = tid; idx < 34 * 34; idx += 256) {
    int r = idx / 34, c = idx % 34;
    int gy = iy0 + r, gx = ix0 + c;
    uint4 v = make_uint4(0u, 0u, 0u, 0u);
    if (gy >= 0 && gy < 60 && gx >= 0 && gx < 80)
      v = *(const uint4*)(src + ((size_t)gy * 80 + gx) * 4);
    sA[0][r][c] = v.x; sA[1][r][c] = v.y; sA[2][r][c] = v.z; sA[3][r][c] = v.w;
  }
  __syncthreads();
  int ly = tid / 16, lx = tid % 16;
  float acc[8][4];
#pragma unroll
  for (int o = 0; o < 8; ++o)
#pragma unroll
    for (int p = 0; p < 4; ++p) acc[o][p] = 0.f;
  const uint4* sW4 = (const uint4*)sW;
#pragma unroll
  for (int icp = 0; icp < 4; ++icp) {
    unsigned int win[16];
#pragma unroll
    for (int r = 0; r < 4; ++r)
#pragma unroll
      for (int c = 0; c < 4; ++c) win[r * 4 + c] = sA[icp][2 * ly + r][2 * lx + c];
#pragma unroll
    for (int tap = 0; tap < 9; ++tap) {
      int ky = tap / 3, kx = tap % 3;
      uint4 wa = sW4[(icp * 9 + tap) * 2];      // oc 0-3
      uint4 wb = sW4[(icp * 9 + tap) * 2 + 1];  // oc 4-7
      unsigned int warr[8] = {wa.x, wa.y, wa.z, wa.w, wb.x, wb.y, wb.z, wb.w};
#pragma unroll
      for (int o = 0; o < 8; ++o) {
#pragma unroll
        for (int py = 0; py < 2; ++py)
#pragma unroll
          for (int px = 0; px < 2; ++px)
            acc[o][py * 2 + px] =
                dot2acc(win[(py + ky) * 4 + (px + kx)], warr[o], acc[o][py * 2 + px]);
      }
    }
  }
  int y = ty0 + ly, x = tx0 + lx;
  if (y < 30 && x < 40) {
#pragma unroll
    for (int o = 0; o < 8; ++o) {
      int oc = ocg * 8 + o;
      float m = fmaxf(fmaxf(acc[o][0], acc[o][1]), fmaxf(acc[o][2], acc[o][3])) + c2b[oc];
      h2[(((size_t)b * 16 + oc) * 30 + y) * 40 + x] = fmaxf(m, 0.f);
    }
  }
}

// ================= K3: fc1 partial GEMM, KS=64, 300 slices, transposed out =============
__global__ __launch_bounds__(256) void k_fc1_part(
    const float* __restrict__ h2, const float* __restrict__ f1w,
    float* __restrict__ fcpart) {
  __shared__ __align__(16) float sH[KS * 68];
  __shared__ __align__(16) float sWt[KS * 68];
  int sl = blockIdx.x, k0 = sl * KS;
  int tid = threadIdx.x;
  for (int idx = tid; idx < 64 * KS; idx += 256) {
    int b = idx >> 6, kk = idx & 63;
    sH[kk * 68 + b] = h2[(size_t)b * 19200 + k0 + kk];
    sWt[kk * 68 + b] = f1w[(size_t)b * 19200 + k0 + kk];
  }
  __syncthreads();
  int bq = tid & 15, jq = tid >> 4;
  int b0 = bq * 4, j0 = jq * 4;
  float acc[4][4];
#pragma unroll
  for (int i = 0; i < 4; ++i)
#pragma unroll
    for (int j = 0; j < 4; ++j) acc[i][j] = 0.f;
  for (int kk = 0; kk < KS; ++kk) {
    float4 hv = *(const float4*)&sH[kk * 68 + b0];
    float4 wv = *(const float4*)&sWt[kk * 68 + j0];
    float hb[4] = {hv.x, hv.y, hv.z, hv.w};
    float wb[4] = {wv.x, wv.y, wv.z, wv.w};
#pragma unroll
    for (int i = 0; i < 4; ++i)
#pragma unroll
      for (int j = 0; j < 4; ++j) acc[i][j] += hb[i] * wb[j];
  }
#pragma unroll
  for (int i = 0; i < 4; ++i)
#pragma unroll
    for (int j = 0; j < 4; ++j)
      fcpart[(size_t)(b0 + i) * 19200 + sl * 64 + (j0 + j)] = acc[i][j];
}

// ================= K4: per-batch fc1-reduce + head + jtr-reduce + solve ================
__global__ __launch_bounds__(256) void k_final(
    const float* __restrict__ fcpart, const float* __restrict__ f1b,
    const float* __restrict__ f2w, const float* __restrict__ f2b,
    const float* __restrict__ consts, const float* __restrict__ part,
    const float* __restrict__ JtJ, const float* __restrict__ poseR,
    const float* __restrict__ poseT, float* __restrict__ out) {
  __shared__ __align__(16) float sred[16 * 64];
  __shared__ float fc1v[64];
  __shared__ float sf2w[384];
  __shared__ float sf2b[8];
  __shared__ float sconst[36];
  __shared__ float lg[6];
  __shared__ float lamv[6];
  __shared__ float jtrv[6];
  int b = blockIdx.x, tid = threadIdx.x;
  for (int i = tid; i < 384; i += 256) sf2w[i] = f2w[i];
  if (tid < 6) sf2b[tid] = f2b[tid];
  if (tid < 36) sconst[tid] = consts[tid];
  {
    const float4* fp4 = (const float4*)(fcpart + (size_t)b * 19200);
    int sg = tid >> 4, j4 = tid & 15;
    float4 a = make_float4(0.f, 0.f, 0.f, 0.f);
    for (int s = sg; s < NSLICE; s += 16) {
      float4 v = fp4[s * 16 + j4];
      a.x += v.x; a.y += v.y; a.z += v.z; a.w += v.w;
    }
    ((float4*)sred)[sg * 16 + j4] = a;
  }
  if (tid >= 64 && tid < 70) {
    int i = tid - 64;
    float v = 0.f;
    for (int s = 0; s < 8; ++s) v += part[(b * 8 + s) * 6 + i];
    jtrv[i] = v;
  }
  __syncthreads();
  if (tid < 64) {
    float v = 0.f;
#pragma unroll
    for (int sg = 0; sg < 16; ++sg) v += sred[sg * 64 + tid];
    fc1v[tid] = fmaxf(v + f1b[tid], 0.f);
  }
  __syncthreads();
  if (tid < 6) {
    float v = sf2b[tid];
#pragma unroll
    for (int k = 0; k < 64; ++k) v += fc1v[k] * sf2w[tid * 64 + k];
    lg[tid] = v;
  }
  __syncthreads();
  if (tid < 6) {
    float m = lg[0];
#pragma unroll
    for (int i = 1; i < 6; ++i) m = fmaxf(m, lg[i]);
    float e[6], ssum = 0.f;
#pragma unroll
    for (int i = 0; i < 6; ++i) { e[i] = expf(lg[i] - m); ssum += e[i]; }
    float inv = 1.f / ssum;
    float wc = 0.f;
#pragma unroll
    for (int i = 0; i < 6; ++i) wc += (e[i] * inv) * sconst[i * 6 + tid];
    float sg = 1.f / (1.f + expf(-wc));
    lamv[tid] = expf((-6.f + sg) * 2.302585092994046f);
  }
  __syncthreads();
  if (tid == 0) {
    float Hm[6][6];
    const float* srcH = JtJ + b * 36;
    float tr = 0.f;
#pragma unroll
    for (int i = 0; i < 6; ++i) {
#pragma unroll
      for (int jj = 0; jj < 6; ++jj) Hm[i][jj] = srcH[i * 6 + jj];
      tr += srcH[i * 6 + i];
    }
    float rhs[6];
#pragma unroll
    for (int i = 0; i < 6; ++i) {
      rhs[i] = jtrv[i];
      Hm[i][i] += lamv[i] + 1e-6f * tr + 1e-6f;
    }
    float L[6][6];
#pragma unroll
    for (int i = 0; i < 6; ++i) {
#pragma unroll
      for (int jj = 0; jj < 6; ++jj) {
        if (jj > i) continue;
        float s = Hm[i][jj];
#pragma unroll
        for (int k = 0; k < 6; ++k)
          if (k < jj) s -= L[i][k] * L[jj][k];
        if (i == jj) L[i][jj] = sqrtf(fmaxf(s, 1e-30f));
        else L[i][jj] = s / L[jj][jj];
      }
    }
    float yv[6];
#pragma unroll
    for (int i = 0; i < 6; ++i) {
      float s = rhs[i];
#pragma unroll
      for (int k = 0; k < 6; ++k)
        if (k < i) s -= L[i][k] * yv[k];
      yv[i] = s / L[i][i];
    }
    float xi[6];
#pragma unroll
    for (int ii = 5; ii >= 0; --ii) {
      float s = yv[ii];
#pragma unroll
      for (int k = 0; k < 6; ++k)
        if (k > ii) s -= L[k][ii] * xi[k];
      xi[ii] = s / L[ii][ii];
    }
    float wx = -xi[0], wy = -xi[1], wz = -xi[2];
    float th = fmaxf(sqrtf(wx * wx + wy * wy + wz * wz), 1e-12f);
    float ux = wx / th, uy = wy / th, uz = wz / th;
    float s = sinf(th), c1 = 1.f - cosf(th);
    float Rd[3][3];
    Rd[0][0] = 1.f + c1 * (ux * ux - 1.f);
    Rd[0][1] = -s * uz + c1 * (ux * uy);
    Rd[0][2] = s * uy + c1 * (ux * uz);
    Rd[1][0] = s * uz + c1 * (uy * ux);
    Rd[1][1] = 1.f + c1 * (uy * uy - 1.f);
    Rd[1][2] = -s * ux + c1 * (uy * uz);
    Rd[2][0] = -s * uy + c1 * (uz * ux);
    Rd[2][1] = s * ux + c1 * (uz * uy);
    Rd[2][2] = 1.f + c1 * (uz * uz - 1.f);
    float dt[3];
#pragma unroll
    for (int r = 0; r < 3; ++r)
      dt[r] = -(Rd[r][0] * xi[3] + Rd[r][1] * xi[4] + Rd[r][2] * xi[5]);
    const float* pR = poseR + b * 9;
    const float* pt = poseT + b * 3;
#pragma unroll
    for (int r = 0; r < 3; ++r) {
#pragma unroll
      for (int cc = 0; cc < 3; ++cc) {
        out[b * 12 + r * 4 + cc] =
            pR[r * 3 + 0] * Rd[0][cc] + pR[r * 3 + 1] * Rd[1][cc] + pR[r * 3 + 2] * Rd[2][cc];
      }
      out[b * 12 + r * 4 + 3] =
          pR[r * 3 + 0] * dt[0] + pR[r * 3 + 1] * dt[1] + pR[r * 3 + 2] * dt[2] + pt[r];
    }
  }
}

extern "C" void kernel_launch(void* const* d_in, const int* in_sizes, int n_in,
                              void* d_out, int out_size, void* d_ws, size_t ws_size,
                              hipStream_t stream) {
  const float* JtJ = (const float*)d_in[0];
  const float* Jt = (const float*)d_in[1];
  const float* wts = (const float*)d_in[2];
  const float* Rin = (const float*)d_in[3];
  const float* poseR = (const float*)d_in[4];
  const float* poseT = (const float*)d_in[5];
  const float* consts = (const float*)d_in[11];
  const float* c1w = (const float*)d_in[12];
  const float* c1b = (const float*)d_in[13];
  const float* c2w = (const float*)d_in[14];
  const float* c2b = (const float*)d_in[15];
  const float* f1w = (const float*)d_in[16];
  const float* f1b = (const float*)d_in[17];
  const float* f2w = (const float*)d_in[18];
  const float* f2b = (const float*)d_in[19];
  float* ws = (float*)d_ws;
  float* part = ws;                               // 3072
  unsigned int* h1u = (unsigned int*)(ws + 3072); // 1,228,800 uints (packed f16 NHWC)
  float* h2 = ws + 3072 + 1228800;                // 1,228,800
  float* fcpart = h2 + 1228800;                   // 1,228,800 ([b][sl][64])
  unsigned int* wpk = (unsigned int*)(fcpart + 1228800);  // 576
  float* out = (float*)d_out;

  k_front<<<dim3(NJTRB + NCONV1), dim3(256), 0, stream>>>(Jt, wts, Rin, c1w, c1b, c2w,
                                                          part, h1u, wpk);
  k_conv2<<<dim3(3, 2, BATCH * 2), dim3(256), 0, stream>>>(h1u, wpk, c2b, h2);
  k_fc1_part<<<dim3(NSLICE), dim3(256), 0, stream>>>(h2, f1w, fcpart);
  k_final<<<dim3(64), dim3(256), 0, stream>>>(fcpart, f1b, f2w, f2b, consts, part,
                                              JtJ, poseR, poseT, out);
}

// Round 12
// 65.144 us; speedup vs baseline: 9.3875x; 1.0356x over previous
//
#include <hip/hip_runtime.h>
#include <math.h>

#define BATCH 64
#define WW 320
#define HWTOT 76800
#define HW4 19200
#define NJTRB 512       // jtr blocks, 8 per batch
#define JSL4 2400       // float4s per jtr block (contiguous)
#define NCONV1 1280
#define KS 64
#define NSLICE 300

typedef _Float16 half2_t __attribute__((ext_vector_type(2)));
union U32H2 { unsigned int u; half2_t h; };
__device__ __forceinline__ unsigned int pack_h2(float a, float b) {
  U32H2 x; x.h = half2_t{(_Float16)a, (_Float16)b}; return x.u;
}
__device__ __forceinline__ half2_t u_as_h2(unsigned int u) { U32H2 x; x.u = u; return x.h; }

#if defined(__has_builtin)
#if __has_builtin(__builtin_amdgcn_fdot2)
#define HAVE_FDOT2 1
#endif
#endif

__device__ __forceinline__ float dot2acc(unsigned int a, unsigned int b, float c) {
#ifdef HAVE_FDOT2
  return __builtin_amdgcn_fdot2(u_as_h2(a), u_as_h2(b), c, false);
#else
  half2_t ah = u_as_h2(a), bh = u_as_h2(b);
  return c + (float)ah.x * (float)bh.x + (float)ah.y * (float)bh.y;
#endif
}

// ================= K1: jtr partials + fused pool+conv1 (h1 -> packed f16 NHWC) ========
__global__ __launch_bounds__(256) void k_front(
    const float* __restrict__ Jt, const float* __restrict__ wgt,
    const float* __restrict__ Rin, const float* __restrict__ c1w,
    const float* __restrict__ c1b, const float* __restrict__ c2w,
    float* __restrict__ part, unsigned int* __restrict__ h1u,
    unsigned int* __restrict__ wpk) {
  __shared__ float smem[34 * 37 + 96];
  int tid = threadIdx.x;
  if (blockIdx.x < NJTRB) {
    int b = blockIdx.x >> 3, s = blockIdx.x & 7;
    const float4* w4 = (const float4*)(wgt + (size_t)b * HWTOT);
    const float4* r4 = (const float4*)(Rin + (size_t)b * HWTOT);
    const float4* j4 = (const float4*)(Jt + (size_t)b * 6 * HWTOT);
    int base = s * JSL4;
    float acc[6] = {0.f, 0.f, 0.f, 0.f, 0.f, 0.f};
#pragma unroll 3
    for (int k = 0; k < 9; ++k) {
      int t = base + k * 256 + tid;
      float4 wv = w4[t], rv = r4[t];
      float4 p;
      p.x = wv.x * rv.x; p.y = wv.y * rv.y; p.z = wv.z * rv.z; p.w = wv.w * rv.w;
#pragma unroll
      for (int i = 0; i < 6; ++i) {
        float4 jv = j4[i * HW4 + t];
        acc[i] += jv.x * p.x + jv.y * p.y + jv.z * p.z + jv.w * p.w;
      }
    }
    if (tid < 96) {
      int t = base + 2304 + tid;
      float4 wv = w4[t], rv = r4[t];
      float4 p;
      p.x = wv.x * rv.x; p.y = wv.y * rv.y; p.z = wv.z * rv.z; p.w = wv.w * rv.w;
#pragma unroll
      for (int i = 0; i < 6; ++i) {
        float4 jv = j4[i * HW4 + t];
        acc[i] += jv.x * p.x + jv.y * p.y + jv.z * p.z + jv.w * p.w;
      }
    }
#pragma unroll
    for (int i = 0; i < 6; ++i) {
      float v = acc[i];
      for (int off = 32; off; off >>= 1) v += __shfl_down(v, off, 64);
      acc[i] = v;
    }
    float* sred = smem;
    int lane = tid & 63, wid = tid >> 6;
    if (lane == 0) {
#pragma unroll
      for (int i = 0; i < 6; ++i) sred[wid * 6 + i] = acc[i];
    }
    __syncthreads();
    if (tid < 6) {
      part[blockIdx.x * 6 + tid] =
          sred[0 + tid] + sred[6 + tid] + sred[12 + tid] + sred[18 + tid];
    }
    return;
  }
  // ---- fused maxpool2(R) + conv1 + relu + maxpool2 -> h1 packed f16 NHWC ----
  int cb = blockIdx.x - NJTRB;
  int b = cb / 20, rem = cb % 20;
  int by = rem / 5, bx = rem % 5;
  // conv2 weight repack on block cb==0: wpk[ocg][tap][o][icp] (uint4-friendly order)
  if (cb == 0) {
    for (int i = tid; i < 576; i += 256) {
      int ocg = i / 288, tap = (i % 288) / 32, o = (i % 32) / 4, icp = i % 4;
      int oc = ocg * 8 + o;
      float lo = c2w[oc * 72 + (2 * icp) * 9 + tap];
      float hi = c2w[oc * 72 + (2 * icp + 1) * 9 + tap];
      wpk[i] = pack_h2(lo, hi);   // i == ocg*288 + tap*32 + o*4 + icp
    }
  }
  float (*sA)[37] = (float(*)[37])smem;
  float* sW = smem + 34 * 37;
  float* sB = sW + 72;
  if (tid < 72) sW[tid] = c1w[(tid & 7) * 9 + (tid >> 3)];
  if (tid < 8) sB[tid] = c1b[tid];
  int iy0 = 32 * by - 1;
  const float* src = Rin + (size_t)b * HWTOT;
  for (int idx = tid; idx < 34 * 18; idx += 256) {
    int pr = idx / 18, c4 = idx % 18;
    int py = iy0 + pr;
    int gx = 64 * bx - 4 + 4 * c4;
    float cell0 = 0.f, cell1 = 0.f;
    if (py >= 0 && py < 120 && gx >= 0 && gx < 320) {
      const float4* row0 = (const float4*)(src + (size_t)(2 * py) * WW + gx);
      const float4* row1 = (const float4*)(src + (size_t)(2 * py + 1) * WW + gx);
      float4 v0 = row0[0], v1 = row1[0];
      cell0 = fmaxf(fmaxf(v0.x, v0.y), fmaxf(v1.x, v1.y));
      cell1 = fmaxf(fmaxf(v0.z, v0.w), fmaxf(v1.z, v1.w));
    }
    sA[pr][2 * c4] = cell0;
    sA[pr][2 * c4 + 1] = cell1;
  }
  __syncthreads();
  int ly = tid / 16, lx = tid % 16;
  int y = 16 * by + ly, x = 16 * bx + lx;
  float win[16];
#pragma unroll
  for (int r = 0; r < 4; ++r)
#pragma unroll
    for (int c = 0; c < 4; ++c) win[r * 4 + c] = sA[2 * ly + r][2 * lx + c + 1];
  float acc[8][4];
#pragma unroll
  for (int oc = 0; oc < 8; ++oc)
#pragma unroll
    for (int p = 0; p < 4; ++p) acc[oc][p] = 0.f;
#pragma unroll
  for (int tap = 0; tap < 9; ++tap) {
    int ky = tap / 3, kx = tap % 3;
#pragma unroll
    for (int oc = 0; oc < 8; ++oc) {
      float wv = sW[tap * 8 + oc];
#pragma unroll
      for (int py = 0; py < 2; ++py)
#pragma unroll
        for (int px = 0; px < 2; ++px)
          acc[oc][py * 2 + px] += wv * win[(py + ky) * 4 + (px + kx)];
    }
  }
  if (y < 60) {
    float v[8];
#pragma unroll
    for (int oc = 0; oc < 8; ++oc)
      v[oc] = fmaxf(fmaxf(fmaxf(acc[oc][0], acc[oc][1]), fmaxf(acc[oc][2], acc[oc][3])) + sB[oc], 0.f);
    uint4 st;
    st.x = pack_h2(v[0], v[1]);
    st.y = pack_h2(v[2], v[3]);
    st.z = pack_h2(v[4], v[5]);
    st.w = pack_h2(v[6], v[7]);
    *(uint4*)(h1u + (((size_t)b * 60 + y) * 80 + x) * 4) = st;
  }
}

// ================= K2: conv2 f16 dot, icp-interleaved LDS, s_load weights =============
// grid (3,2,B*2), z = b*2 + ocg. h1u = packed f16 NHWC (uint4/cell = 4 ic-pairs).
__global__ __launch_bounds__(256) void k_conv2(
    const unsigned int* __restrict__ h1u, const unsigned int* __restrict__ wpk,
    const float* __restrict__ c2b, float* __restrict__ h2) {
  __shared__ __align__(16) uint4 sA[34][36];   // [row][col] = 4 ic-pair h2 values
  int b = blockIdx.z >> 1, ocg = blockIdx.z & 1;
  int ty0 = blockIdx.y * 16, tx0 = blockIdx.x * 16;
  int tid = threadIdx.x;
  int iy0 = ty0 * 2 - 1, ix0 = tx0 * 2 - 1;
  const unsigned int* src = h1u + (size_t)b * 60 * 80 * 4;
  for (int idx = tid; idx < 34 * 34; idx += 256) {
    int r = idx / 34, c = idx % 34;
    int gy = iy0 + r, gx = ix0 + c;
    uint4 v = make_uint4(0u, 0u, 0u, 0u);
    if (gy >= 0 && gy < 60 && gx >= 0 && gx < 80)
      v = *(const uint4*)(src + ((size_t)gy * 80 + gx) * 4);
    sA[r][c] = v;
  }
  __syncthreads();
  int ly = tid / 16, lx = tid % 16;
  // win[p] = uint4 of all 4 icp at that window cell — 16 ds_read_b128 total
  uint4 win[16];
#pragma unroll
  for (int r = 0; r < 4; ++r)
#pragma unroll
    for (int c = 0; c < 4; ++c) win[r * 4 + c] = sA[2 * ly + r][2 * lx + c];
  float acc[8][4];
#pragma unroll
  for (int o = 0; o < 8; ++o)
#pragma unroll
    for (int p = 0; p < 4; ++p) acc[o][p] = 0.f;
  // weights: wave-uniform uint4 loads (s_load_dwordx4), [tap][o] -> 4 icp pairs
  const uint4* wq = (const uint4*)wpk + ocg * 72;
#pragma unroll
  for (int tap = 0; tap < 9; ++tap) {
    int ky = tap / 3, kx = tap % 3;
#pragma unroll
    for (int o = 0; o < 8; ++o) {
      uint4 wv = wq[tap * 8 + o];   // .x..w = icp 0..3
#pragma unroll
      for (int py = 0; py < 2; ++py)
#pragma unroll
        for (int px = 0; px < 2; ++px) {
          uint4 wn = win[(py + ky) * 4 + (px + kx)];
          float a = acc[o][py * 2 + px];
          a = dot2acc(wn.x, wv.x, a);
          a = dot2acc(wn.y, wv.y, a);
          a = dot2acc(wn.z, wv.z, a);
          a = dot2acc(wn.w, wv.w, a);
          acc[o][py * 2 + px] = a;
        }
    }
  }
  int y = ty0 + ly, x = tx0 + lx;
  if (y < 30 && x < 40) {
#pragma unroll
    for (int o = 0; o < 8; ++o) {
      int oc = ocg * 8 + o;
      float m = fmaxf(fmaxf(acc[o][0], acc[o][1]), fmaxf(acc[o][2], acc[o][3])) + c2b[oc];
      h2[(((size_t)b * 16 + oc) * 30 + y) * 40 + x] = fmaxf(m, 0.f);
    }
  }
}

// ================= K3: fc1 partial GEMM, KS=64, 300 slices, transposed out =============
__global__ __launch_bounds__(256) void k_fc1_part(
    const float* __restrict__ h2, const float* __restrict__ f1w,
    float* __restrict__ fcpart) {
  __shared__ __align__(16) float sH[KS * 68];
  __shared__ __align__(16) float sWt[KS * 68];
  int sl = blockIdx.x, k0 = sl * KS;
  int tid = threadIdx.x;
  for (int idx = tid; idx < 64 * KS; idx += 256) {
    int b = idx >> 6, kk = idx & 63;
    sH[kk * 68 + b] = h2[(size_t)b * 19200 + k0 + kk];
    sWt[kk * 68 + b] = f1w[(size_t)b * 19200 + k0 + kk];
  }
  __syncthreads();
  int bq = tid & 15, jq = tid >> 4;
  int b0 = bq * 4, j0 = jq * 4;
  float acc[4][4];
#pragma unroll
  for (int i = 0; i < 4; ++i)
#pragma unroll
    for (int j = 0; j < 4; ++j) acc[i][j] = 0.f;
  for (int kk = 0; kk < KS; ++kk) {
    float4 hv = *(const float4*)&sH[kk * 68 + b0];
    float4 wv = *(const float4*)&sWt[kk * 68 + j0];
    float hb[4] = {hv.x, hv.y, hv.z, hv.w};
    float wb[4] = {wv.x, wv.y, wv.z, wv.w};
#pragma unroll
    for (int i = 0; i < 4; ++i)
#pragma unroll
      for (int j = 0; j < 4; ++j) acc[i][j] += hb[i] * wb[j];
  }
#pragma unroll
  for (int i = 0; i < 4; ++i)
#pragma unroll
    for (int j = 0; j < 4; ++j)
      fcpart[(size_t)(b0 + i) * 19200 + sl * 64 + (j0 + j)] = acc[i][j];
}

// ================= K4: per-batch fc1-reduce + head + jtr-reduce + solve ================
__global__ __launch_bounds__(256) void k_final(
    const float* __restrict__ fcpart, const float* __restrict__ f1b,
    const float* __restrict__ f2w, const float* __restrict__ f2b,
    const float* __restrict__ consts, const float* __restrict__ part,
    const float* __restrict__ JtJ, const float* __restrict__ poseR,
    const float* __restrict__ poseT, float* __restrict__ out) {
  __shared__ __align__(16) float sred[16 * 64];
  __shared__ float fc1v[64];
  __shared__ float sf2w[384];
  __shared__ float sf2b[8];
  __shared__ float sconst[36];
  __shared__ float lg[6];
  __shared__ float lamv[6];
  __shared__ float jtrv[6];
  int b = blockIdx.x, tid = threadIdx.x;
  for (int i = tid; i < 384; i += 256) sf2w[i] = f2w[i];
  if (tid < 6) sf2b[tid] = f2b[tid];
  if (tid < 36) sconst[tid] = consts[tid];
  {
    const float4* fp4 = (const float4*)(fcpart + (size_t)b * 19200);
    int sg = tid >> 4, j4 = tid & 15;
    float4 a = make_float4(0.f, 0.f, 0.f, 0.f);
    for (int s = sg; s < NSLICE; s += 16) {
      float4 v = fp4[s * 16 + j4];
      a.x += v.x; a.y += v.y; a.z += v.z; a.w += v.w;
    }
    ((float4*)sred)[sg * 16 + j4] = a;
  }
  if (tid >= 64 && tid < 70) {
    int i = tid - 64;
    float v = 0.f;
    for (int s = 0; s < 8; ++s) v += part[(b * 8 + s) * 6 + i];
    jtrv[i] = v;
  }
  __syncthreads();
  if (tid < 64) {
    float v = 0.f;
#pragma unroll
    for (int sg = 0; sg < 16; ++sg) v += sred[sg * 64 + tid];
    fc1v[tid] = fmaxf(v + f1b[tid], 0.f);
  }
  __syncthreads();
  if (tid < 6) {
    float v = sf2b[tid];
#pragma unroll
    for (int k = 0; k < 64; ++k) v += fc1v[k] * sf2w[tid * 64 + k];
    lg[tid] = v;
  }
  __syncthreads();
  if (tid < 6) {
    float m = lg[0];
#pragma unroll
    for (int i = 1; i < 6; ++i) m = fmaxf(m, lg[i]);
    float e[6], ssum = 0.f;
#pragma unroll
    for (int i = 0; i < 6; ++i) { e[i] = expf(lg[i] - m); ssum += e[i]; }
    float inv = 1.f / ssum;
    float wc = 0.f;
#pragma unroll
    for (int i = 0; i < 6; ++i) wc += (e[i] * inv) * sconst[i * 6 + tid];
    float sg = 1.f / (1.f + expf(-wc));
    lamv[tid] = expf((-6.f + sg) * 2.302585092994046f);
  }
  __syncthreads();
  if (tid == 0) {
    float Hm[6][6];
    const float* srcH = JtJ + b * 36;
    float tr = 0.f;
#pragma unroll
    for (int i = 0; i < 6; ++i) {
#pragma unroll
      for (int jj = 0; jj < 6; ++jj) Hm[i][jj] = srcH[i * 6 + jj];
      tr += srcH[i * 6 + i];
    }
    float rhs[6];
#pragma unroll
    for (int i = 0; i < 6; ++i) {
      rhs[i] = jtrv[i];
      Hm[i][i] += lamv[i] + 1e-6f * tr + 1e-6f;
    }
    float L[6][6];
#pragma unroll
    for (int i = 0; i < 6; ++i) {
#pragma unroll
      for (int jj = 0; jj < 6; ++jj) {
        if (jj > i) continue;
        float s = Hm[i][jj];
#pragma unroll
        for (int k = 0; k < 6; ++k)
          if (k < jj) s -= L[i][k] * L[jj][k];
        if (i == jj) L[i][jj] = sqrtf(fmaxf(s, 1e-30f));
        else L[i][jj] = s / L[jj][jj];
      }
    }
    float yv[6];
#pragma unroll
    for (int i = 0; i < 6; ++i) {
      float s = rhs[i];
#pragma unroll
      for (int k = 0; k < 6; ++k)
        if (k < i) s -= L[i][k] * yv[k];
      yv[i] = s / L[i][i];
    }
    float xi[6];
#pragma unroll
    for (int ii = 5; ii >= 0; --ii) {
      float s = yv[ii];
#pragma unroll
      for (int k = 0; k < 6; ++k)
        if (k > ii) s -= L[k][ii] * xi[k];
      xi[ii] = s / L[ii][ii];
    }
    float wx = -xi[0], wy = -xi[1], wz = -xi[2];
    float th = fmaxf(sqrtf(wx * wx + wy * wy + wz * wz), 1e-12f);
    float ux = wx / th, uy = wy / th, uz = wz / th;
    float s = sinf(th), c1 = 1.f - cosf(th);
    float Rd[3][3];
    Rd[0][0] = 1.f + c1 * (ux * ux - 1.f);
    Rd[0][1] = -s * uz + c1 * (ux * uy);
    Rd[0][2] = s * uy + c1 * (ux * uz);
    Rd[1][0] = s * uz + c1 * (uy * ux);
    Rd[1][1] = 1.f + c1 * (uy * uy - 1.f);
    Rd[1][2] = -s * ux + c1 * (uy * uz);
    Rd[2][0] = -s * uy + c1 * (uz * ux);
    Rd[2][1] = s * ux + c1 * (uz * uy);
    Rd[2][2] = 1.f + c1 * (uz * uz - 1.f);
    float dt[3];
#pragma unroll
    for (int r = 0; r < 3; ++r)
      dt[r] = -(Rd[r][0] * xi[3] + Rd[r][1] * xi[4] + Rd[r][2] * xi[5]);
    const float* pR = poseR + b * 9;
    const float* pt = poseT + b * 3;
#pragma unroll
    for (int r = 0; r < 3; ++r) {
#pragma unroll
      for (int cc = 0; cc < 3; ++cc) {
        out[b * 12 + r * 4 + cc] =
            pR[r * 3 + 0] * Rd[0][cc] + pR[r * 3 + 1] * Rd[1][cc] + pR[r * 3 + 2] * Rd[2][cc];
      }
      out[b * 12 + r * 4 + 3] =
          pR[r * 3 + 0] * dt[0] + pR[r * 3 + 1] * dt[1] + pR[r * 3 + 2] * dt[2] + pt[r];
    }
  }
}

extern "C" void kernel_launch(void* const* d_in, const int* in_sizes, int n_in,
                              void* d_out, int out_size, void* d_ws, size_t ws_size,
                              hipStream_t stream) {
  const float* JtJ = (const float*)d_in[0];
  const float* Jt = (const float*)d_in[1];
  const float* wts = (const float*)d_in[2];
  const float* Rin = (const float*)d_in[3];
  const float* poseR = (const float*)d_in[4];
  const float* poseT = (const float*)d_in[5];
  const float* consts = (const float*)d_in[11];
  const float* c1w = (const float*)d_in[12];
  const float* c1b = (const float*)d_in[13];
  const float* c2w = (const float*)d_in[14];
  const float* c2b = (const float*)d_in[15];
  const float* f1w = (const float*)d_in[16];
  const float* f1b = (const float*)d_in[17];
  const float* f2w = (const float*)d_in[18];
  const float* f2b = (const float*)d_in[19];
  float* ws = (float*)d_ws;
  float* part = ws;                               // 3072
  unsigned int* h1u = (unsigned int*)(ws + 3072); // 1,228,800 uints (packed f16 NHWC)
  float* h2 = ws + 3072 + 1228800;                // 1,228,800
  float* fcpart = h2 + 1228800;                   // 1,228,800 ([b][sl][64])
  unsigned int* wpk = (unsigned int*)(fcpart + 1228800);  // 576
  float* out = (float*)d_out;

  k_front<<<dim3(NJTRB + NCONV1), dim3(256), 0, stream>>>(Jt, wts, Rin, c1w, c1b, c2w,
                                                          part, h1u, wpk);
  k_conv2<<<dim3(3, 2, BATCH * 2), dim3(256), 0, stream>>>(h1u, wpk, c2b, h2);
  k_fc1_part<<<dim3(NSLICE), dim3(256), 0, stream>>>(h2, f1w, fcpart);
  k_final<<<dim3(64), dim3(256), 0, stream>>>(fcpart, f1b, f2w, f2b, consts, part,
                                              JtJ, poseR, poseT, out);
}